// Round 3
// baseline (366.687 us; speedup 1.0000x reference)
//
#include <hip/hip_runtime.h>
#include <math.h>

struct Plan { float tiles, tlx, tly, brx, bry, fm; };

__device__ __forceinline__ Plan process_one(
    float p0, float p1, float p2, float4 q,
    float s0, float s1, float s2,
    float c0, float c1, float c2, float op,
    const float* __restrict__ E, const float* __restrict__ I,
    float fx, float fy, float fw, float fh, float rtile,
    float limX, float limY, int max_tx, int max_ty,
    float4* __restrict__ rowptr)
{
    // ---- quaternion -> rotation ----
    const float rq = rsqrtf(q.x*q.x + q.y*q.y + q.z*q.z + q.w*q.w);
    const float qr = q.x * rq, qx = q.y * rq, qy = q.z * rq, qz = q.w * rq;

    const float r00 = 1.0f - 2.0f * (qy*qy + qz*qz);
    const float r01 = 2.0f * (qx*qy - qr*qz);
    const float r02 = 2.0f * (qx*qz + qr*qy);
    const float r10 = 2.0f * (qx*qy + qr*qz);
    const float r11 = 1.0f - 2.0f * (qx*qx + qz*qz);
    const float r12 = 2.0f * (qy*qz - qr*qx);
    const float r20 = 2.0f * (qx*qz - qr*qy);
    const float r21 = 2.0f * (qy*qz + qr*qx);
    const float r22 = 1.0f - 2.0f * (qx*qx + qy*qy);

    const float m00 = r00*s0, m01 = r01*s1, m02 = r02*s2;
    const float m10 = r10*s0, m11 = r11*s1, m12 = r12*s2;
    const float m20 = r20*s0, m21 = r21*s1, m22 = r22*s2;

    const float S00 = m00*m00 + m01*m01 + m02*m02;
    const float S01 = m00*m10 + m01*m11 + m02*m12;
    const float S02 = m00*m20 + m01*m21 + m02*m22;
    const float S11 = m10*m10 + m11*m11 + m12*m12;
    const float S12 = m10*m20 + m11*m21 + m12*m22;
    const float S22 = m20*m20 + m21*m21 + m22*m22;

    const float pc0 = p0*E[0] + p1*E[4] + p2*E[8]  + E[12];
    const float pc1 = p0*E[1] + p1*E[5] + p2*E[9]  + E[13];
    const float pc2 = p0*E[2] + p1*E[6] + p2*E[10] + E[14];
    const float pc3 = p0*E[3] + p1*E[7] + p2*E[11] + E[15];

    const float zc = pc2;
    const bool  zmask = zc > 0.2f;
    const float z_safe = zmask ? zc : 1.0f;
    const float rz = __builtin_amdgcn_rcpf(z_safe);

    const float xx = fminf(fmaxf(pc0 * rz, -limX), limX) * zc;
    const float yy = fminf(fmaxf(pc1 * rz, -limY), limY) * zc;

    const float j00 = fx * rz;
    const float j02 = -(fx * xx) * rz * rz;
    const float j11 = fy * rz;
    const float j12 = -(fy * yy) * rz * rz;

    const float t00 = E[0]*j00 + E[2]*j02;
    const float t01 = E[4]*j00 + E[6]*j02;
    const float t02 = E[8]*j00 + E[10]*j02;
    const float t10 = E[1]*j11 + E[2]*j12;
    const float t11 = E[5]*j11 + E[6]*j12;
    const float t12 = E[9]*j11 + E[10]*j12;

    const float v00 = S00*t00 + S01*t01 + S02*t02;
    const float v01 = S01*t00 + S11*t01 + S12*t02;
    const float v02 = S02*t00 + S12*t01 + S22*t02;
    const float v10 = S00*t10 + S01*t11 + S02*t12;
    const float v11 = S01*t10 + S11*t11 + S12*t12;
    const float v12 = S02*t10 + S12*t11 + S22*t12;

    const float a = (t00*v00 + t01*v01 + t02*v02) + 0.3f;
    const float b = (t00*v10 + t01*v11 + t02*v12);
    const float c = (t10*v00 + t11*v01 + t12*v02);
    const float d = (t10*v10 + t11*v11 + t12*v12) + 0.3f;

    const float n0 = pc0*I[0] + pc1*I[4] + pc2*I[8]  + pc3*I[12];
    const float n1 = pc0*I[1] + pc1*I[5] + pc2*I[9]  + pc3*I[13];
    const float n2 = pc0*I[2] + pc1*I[6] + pc2*I[10] + pc3*I[14];
    const float n3 = pc0*I[3] + pc1*I[7] + pc2*I[11] + pc3*I[15];

    const float w_safe = zmask ? n3 : 1.0f;
    const float rw = __builtin_amdgcn_rcpf(w_safe);
    const float nx = n0 * rw;
    const float ny = n1 * rw;
    const float nz = n2;

    const bool mask = (nz > 0.2f) && (nx < 1.3f) && (nx > -1.3f)
                                  && (ny < 1.3f) && (ny > -1.3f);
    const float fm = mask ? 1.0f : 0.0f;

    const float det = a*d - b*c;
    const float det_safe = (fabsf(det) < 1e-12f) ? 1e-12f : det;
    const float rdet = __builtin_amdgcn_rcpf(det_safe);
    const float inv00 =  d * rdet;
    const float inv01 = -b * rdet;
    const float inv10 = -c * rdet;
    const float inv11 =  a * rdet;

    const float mid = 0.5f * (a + d);
    const float sq  = sqrtf(fmaxf(mid*mid - det, 0.1f));
    const float lmax = fmaxf(mid + sq, mid - sq);
    const float radius = ceilf(3.0f * sqrtf(fmaxf(lmax, 1e-6f)));

    const float px = ((nx + 1.0f) * fw - 1.0f) * 0.5f;
    const float py = ((ny + 1.0f) * fh - 1.0f) * 0.5f;

    int tlx = (int)((px - radius) * rtile);
    int tly = (int)((py - radius) * rtile);
    int brx = (int)((px + radius) * rtile);
    int bry = (int)((py + radius) * rtile);
    tlx = min(max(tlx, 0), max_tx);
    tly = min(max(tly, 0), max_ty);
    brx = min(max(brx, 0), max_tx);
    bry = min(max(bry, 0), max_ty);

    const int sx = max(brx + 1 - tlx, 1);
    const int sy = max(bry + 1 - tly, 1);

    rowptr[0] = make_float4(px*fm, py*fm, nz*fm, a*fm);
    rowptr[1] = make_float4(b*fm, c*fm, d*fm, inv00*fm);
    rowptr[2] = make_float4(inv01*fm, inv10*fm, inv11*fm, radius*fm);
    rowptr[3] = make_float4(c0*fm, c1*fm, c2*fm, op*fm);

    Plan pl;
    pl.tiles = mask ? (float)(sx * sy) : 0.0f;
    pl.tlx = (float)tlx; pl.tly = (float)tly;
    pl.brx = (float)brx; pl.bry = (float)bry;
    pl.fm = fm;
    return pl;
}

__global__ __launch_bounds__(256) void gs_fwd4(
    const float* __restrict__ points,
    const float* __restrict__ quats,
    const float* __restrict__ scales,
    const float* __restrict__ colors,
    const float* __restrict__ opac,
    const float* __restrict__ E,
    const float* __restrict__ I,
    const int* __restrict__ p_fx,
    const int* __restrict__ p_fy,
    const int* __restrict__ p_w,
    const int* __restrict__ p_h,
    const int* __restrict__ p_tile,
    float* __restrict__ out,
    int N)
{
    const int j = blockIdx.x * blockDim.x + threadIdx.x;
    const int g0 = j * 4;
    if (g0 >= N) return;

    const float fx = (float)p_fx[0];
    const float fy = (float)p_fy[0];
    const float fw = (float)p_w[0];
    const float fh = (float)p_h[0];
    const float ftile = (float)p_tile[0];
    const float rtile = __builtin_amdgcn_rcpf(ftile);
    const float tanX = fw / (2.0f * fx);
    const float tanY = fh / (2.0f * fy);
    const float limX = 1.3f * tanX;
    const float limY = 1.3f * tanY;
    const int max_tx = (int)ceilf(fw * rtile) - 1;
    const int max_ty = (int)ceilf(fh * rtile) - 1;

    const size_t nb = (size_t)N;
    const size_t base = nb * 16;

    if (g0 + 3 < N && (N & 3) == 0) {
        // ---- fully vectorized 4-gaussian path ----
        const float4* P4 = reinterpret_cast<const float4*>(points);
        const float4* Q4 = reinterpret_cast<const float4*>(quats);
        const float4* S4 = reinterpret_cast<const float4*>(scales);
        const float4* C4 = reinterpret_cast<const float4*>(colors);
        const float4* O4 = reinterpret_cast<const float4*>(opac);

        const float4 pA = P4[3*j], pB = P4[3*j+1], pC = P4[3*j+2];
        const float4 q0v = Q4[4*j], q1v = Q4[4*j+1], q2v = Q4[4*j+2], q3v = Q4[4*j+3];
        const float4 sA = S4[3*j], sB = S4[3*j+1], sC = S4[3*j+2];
        const float4 cA = C4[3*j], cB = C4[3*j+1], cC = C4[3*j+2];
        const float4 ov = O4[j];

        float4* row = reinterpret_cast<float4*>(out + (size_t)g0 * 16);

        Plan pl0 = process_one(pA.x, pA.y, pA.z, q0v, sA.x, sA.y, sA.z,
                               cA.x, cA.y, cA.z, ov.x, E, I,
                               fx, fy, fw, fh, rtile, limX, limY, max_tx, max_ty,
                               row + 0);
        Plan pl1 = process_one(pA.w, pB.x, pB.y, q1v, sA.w, sB.x, sB.y,
                               cA.w, cB.x, cB.y, ov.y, E, I,
                               fx, fy, fw, fh, rtile, limX, limY, max_tx, max_ty,
                               row + 4);
        Plan pl2 = process_one(pB.z, pB.w, pC.x, q2v, sB.z, sB.w, sC.x,
                               cB.z, cB.w, cC.x, ov.z, E, I,
                               fx, fy, fw, fh, rtile, limX, limY, max_tx, max_ty,
                               row + 8);
        Plan pl3 = process_one(pC.y, pC.z, pC.w, q3v, sC.y, sC.z, sC.w,
                               cC.y, cC.z, cC.w, ov.w, E, I,
                               fx, fy, fw, fh, rtile, limX, limY, max_tx, max_ty,
                               row + 12);

        float* ob = out + base;
        reinterpret_cast<float4*>(ob)[j]          = make_float4(pl0.tiles, pl1.tiles, pl2.tiles, pl3.tiles);
        reinterpret_cast<float4*>(ob + nb)[j]     = make_float4(pl0.tlx, pl1.tlx, pl2.tlx, pl3.tlx);
        reinterpret_cast<float4*>(ob + 2*nb)[j]   = make_float4(pl0.tly, pl1.tly, pl2.tly, pl3.tly);
        reinterpret_cast<float4*>(ob + 3*nb)[j]   = make_float4(pl0.brx, pl1.brx, pl2.brx, pl3.brx);
        reinterpret_cast<float4*>(ob + 4*nb)[j]   = make_float4(pl0.bry, pl1.bry, pl2.bry, pl3.bry);
        reinterpret_cast<float4*>(ob + 5*nb)[j]   = make_float4(pl0.fm, pl1.fm, pl2.fm, pl3.fm);
    } else {
        // ---- scalar tail (any N) ----
        for (int i = g0; i < N && i < g0 + 4; ++i) {
            const float4 q = make_float4(quats[4*i], quats[4*i+1], quats[4*i+2], quats[4*i+3]);
            float4* row = reinterpret_cast<float4*>(out + (size_t)i * 16);
            Plan pl = process_one(points[3*i], points[3*i+1], points[3*i+2], q,
                                  scales[3*i], scales[3*i+1], scales[3*i+2],
                                  colors[3*i], colors[3*i+1], colors[3*i+2],
                                  opac[i], E, I,
                                  fx, fy, fw, fh, rtile, limX, limY, max_tx, max_ty,
                                  row);
            out[base + i]        = pl.tiles;
            out[base + nb + i]   = pl.tlx;
            out[base + 2*nb + i] = pl.tly;
            out[base + 3*nb + i] = pl.brx;
            out[base + 4*nb + i] = pl.bry;
            out[base + 5*nb + i] = pl.fm;
        }
    }
}

extern "C" void kernel_launch(void* const* d_in, const int* in_sizes, int n_in,
                              void* d_out, int out_size, void* d_ws, size_t ws_size,
                              hipStream_t stream) {
    const float* points = (const float*)d_in[0];
    const float* quats  = (const float*)d_in[1];
    const float* scales = (const float*)d_in[2];
    const float* colors = (const float*)d_in[3];
    const float* opac   = (const float*)d_in[4];
    const float* E      = (const float*)d_in[5];
    const float* I      = (const float*)d_in[6];
    const int* p_fx   = (const int*)d_in[7];
    const int* p_fy   = (const int*)d_in[8];
    const int* p_w    = (const int*)d_in[9];
    const int* p_h    = (const int*)d_in[10];
    const int* p_tile = (const int*)d_in[11];

    const int N = in_sizes[4];   // opacity has exactly N elements
    const int block = 256;
    const int nthreads = (N + 3) / 4;
    const int grid = (nthreads + block - 1) / block;
    gs_fwd4<<<grid, block, 0, stream>>>(points, quats, scales, colors, opac,
                                        E, I, p_fx, p_fy, p_w, p_h, p_tile,
                                        (float*)d_out, N);
}